// Round 3
// baseline (73.241 us; speedup 1.0000x reference)
//
#include <hip/hip_runtime.h>
#include <math.h>

// B=16, T=64, R=256, C=16, D=16, O(=in_dim)=16, NUM_ITERATIONS=3
//
// Factorization: u_hat[b,t,r,c,o] = Wsum[r,c,o]*usum[b,t]
//   Wsum[r,c,o] = sum_d W[r,c,d,o], usum[b,t] = sum_i ui[b,t,i]
// Per routing iter:
//   c_ij = softmax_c(b_ij); S[b,c,o] = sum_r c_ij*Wsum; NS[b,c]=sum_o S^2
//   scale(b,t,c) = squash_scale(usum^2*NS)
//   b_ij += WS[b,r,c]*Tsum[b,c],  WS = sum_o Wsum*S, Tsum = sum_t usum^2*scale
// Iter 0: c_ij uniform 1/16 -> S0[c,o] = (sum_r Wsum)/16 (b-independent).
// Output: v[b,t,c,o] = scale(b,t,c)*usum[b,t]*S2[b,c,o]
//
// RACE NOTE (R2 lesson): one block per (b,c) means softmax (reads all 16
// columns of bij) races with sibling blocks' column writes if done in-place.
// => double-buffer: iter1 reads BIJ, writes BIJ2; iter2 reads BIJ2.

// workspace float offsets
#define OFF_WSUM   0        // [256][16][16] (r,c,o)
#define OFF_WSUMT  65536    // [16][16][256] (c,o,r)
#define OFF_USUM   131072   // [16][64]      (b,t)
#define OFF_BIJ    132096   // [16][256][16] (b,r,c)   logits after iter 0
#define OFF_BIJ2   197632   // [16][256][16] (b,r,c)   logits after iter 1

__device__ __forceinline__ float squash_scale(float n2) {
    return n2 / (1.0f + n2) * rsqrtf(n2 + 1e-9f);
}

// K1: Wsum (both layouts) + usum. grid 260x256
__global__ void k1_prep(const float* __restrict__ ui, const float* __restrict__ W,
                        float* __restrict__ ws) {
    const int blk = blockIdx.x;
    const int tid = threadIdx.x;
    if (blk < 256) {
        const int r = blk;
        const int c = tid >> 4, o = tid & 15;
        const float* base = W + r * 4096 + c * 256 + o;
        float s = 0.f;
#pragma unroll
        for (int d = 0; d < 16; ++d) s += base[d * 16];
        ws[OFF_WSUM + r * 256 + tid] = s;
        ws[OFF_WSUMT + tid * 256 + r] = s;
    } else {
        const int p = (blk - 256) * 256 + tid;   // b*64+t
        const float* base = ui + p * 16;
        float s = 0.f;
#pragma unroll
        for (int i = 0; i < 16; ++i) s += base[i];
        ws[OFF_USUM + p] = s;
    }
}

// K2: closed-form iteration 0 -> bij after iter0. One block per (b,c). grid 256.
__global__ void k2_round0(float* __restrict__ ws) {
    __shared__ float part[16][17];
    __shared__ float S0[16];
    __shared__ float nsTs[2];         // [0]=NS0, [1]=Tsum0
    __shared__ float usum_sh[64];
    const int bid = blockIdx.x;
    const int b = bid >> 4, c = bid & 15;
    const int tid = threadIdx.x;
    if (tid < 64) usum_sh[tid] = ws[OFF_USUM + b * 64 + tid];

    // S0[o] = (1/16) sum_r WsumT[c,o,r]; thread=(o, rq) sums 16 r's
    {
        const int o = tid >> 4, rq = tid & 15;
        const float4* wt = (const float4*)(ws + OFF_WSUMT + (c * 16 + o) * 256 + rq * 16);
        float acc = 0.f;
#pragma unroll
        for (int q = 0; q < 4; ++q) {
            float4 w = wt[q];
            acc += (w.x + w.y) + (w.z + w.w);
        }
        part[o][rq] = acc;
    }
    __syncthreads();
    if (tid < 16) {
        float s = 0.f;
#pragma unroll
        for (int k = 0; k < 16; ++k) s += part[tid][k];
        S0[tid] = s * (1.0f / 16.0f);
    }
    __syncthreads();
    if (tid == 0) {
        float ns = 0.f;
#pragma unroll
        for (int o = 0; o < 16; ++o) ns += S0[o] * S0[o];
        nsTs[0] = ns;
    }
    __syncthreads();
    if (tid < 64) {                    // Tsum0: single-wave reduce over t
        const float us = usum_sh[tid];
        const float us2 = us * us;
        float v = us2 * squash_scale(us2 * nsTs[0]);
#pragma unroll
        for (int off = 32; off > 0; off >>= 1) v += __shfl_down(v, off, 64);
        if (tid == 0) nsTs[1] = v;
    }
    __syncthreads();
    // bij[b,r,c] = (sum_o Wsum[r,c,o]*S0[o]) * Tsum0
    {
        const int r = tid;
        const float4* w4 = (const float4*)(ws + OFF_WSUM + r * 256 + c * 16);
        const float4* s4 = (const float4*)S0;
        float wsv = 0.f;
#pragma unroll
        for (int q = 0; q < 4; ++q) {
            float4 w = w4[q]; float4 sv = s4[q];
            wsv += w.x * sv.x + w.y * sv.y + w.z * sv.z + w.w * sv.w;
        }
        ws[OFF_BIJ + b * 4096 + r * 16 + c] = wsv * nsTs[1];
    }
}

// K3: one routing iteration. One block per (b,c). grid 256.
// FINAL=false: read bij from SRC, write SRC+delta into DST (disjoint buffer).
// FINAL=true:  read bij from SRC, write v_j output.
template <bool FINAL>
__global__ void k3_iter(float* __restrict__ ws, float* __restrict__ out,
                        int srcOff, int dstOff) {
    __shared__ float cij[256];        // softmax prob for THIS block's c, per r
    __shared__ float part[16][17];
    __shared__ float S[16];
    __shared__ float nsTs[2];
    __shared__ float usum_sh[64];
    const int bid = blockIdx.x;
    const int b = bid >> 4, c = bid & 15;
    const int tid = threadIdx.x;
    if (tid < 64) usum_sh[tid] = ws[OFF_USUM + b * 64 + tid];

    // softmax over c of src_bij[b, r=tid, :], keep element c; remember own logit
    float ownLogit;
    {
        const float4* r4 = (const float4*)(ws + srcOff + b * 4096 + tid * 16);
        float v[16];
        float4* rv = (float4*)v;
#pragma unroll
        for (int q = 0; q < 4; ++q) rv[q] = r4[q];
        ownLogit = v[c];
        float m = v[0];
#pragma unroll
        for (int k = 1; k < 16; ++k) m = fmaxf(m, v[k]);
        float sum = 0.f;
#pragma unroll
        for (int k = 0; k < 16; ++k) { v[k] = __expf(v[k] - m); sum += v[k]; }
        cij[tid] = v[c] / sum;
    }
    __syncthreads();

    // S[o] = sum_r cij[r]*WsumT[c,o,r]; thread=(o, rq)
    {
        const int o = tid >> 4, rq = tid & 15;
        const float4* wt = (const float4*)(ws + OFF_WSUMT + (c * 16 + o) * 256 + rq * 16);
        float acc = 0.f;
#pragma unroll
        for (int q = 0; q < 4; ++q) {
            float4 w = wt[q];
            const int base = rq * 16 + q * 4;
            acc += cij[base] * w.x + cij[base + 1] * w.y
                 + cij[base + 2] * w.z + cij[base + 3] * w.w;
        }
        part[o][rq] = acc;
    }
    __syncthreads();
    if (tid < 16) {
        float s = 0.f;
#pragma unroll
        for (int k = 0; k < 16; ++k) s += part[tid][k];
        S[tid] = s;
    }
    __syncthreads();
    if (tid == 0) {
        float ns = 0.f;
#pragma unroll
        for (int o = 0; o < 16; ++o) ns += S[o] * S[o];
        nsTs[0] = ns;
    }
    __syncthreads();

    if (!FINAL) {
        if (tid < 64) {                // Tsum: single-wave reduce
            const float us = usum_sh[tid];
            const float us2 = us * us;
            float v = us2 * squash_scale(us2 * nsTs[0]);
#pragma unroll
            for (int off = 32; off > 0; off >>= 1) v += __shfl_down(v, off, 64);
            if (tid == 0) nsTs[1] = v;
        }
        __syncthreads();
        const int r = tid;
        const float4* w4 = (const float4*)(ws + OFF_WSUM + r * 256 + c * 16);
        const float4* s4 = (const float4*)S;
        float wsv = 0.f;
#pragma unroll
        for (int q = 0; q < 4; ++q) {
            float4 w = w4[q]; float4 sv = s4[q];
            wsv += w.x * sv.x + w.y * sv.y + w.z * sv.z + w.w * sv.w;
        }
        ws[dstOff + b * 4096 + r * 16 + c] = ownLogit + wsv * nsTs[1];
    } else {
        // v[b,t,c,o] = squash_scale(us^2*NS)*us*S[o]; thread=(t, o-quad)
        const int t = tid >> 2, oq = tid & 3;
        const float us = usum_sh[t];
        const float n2 = us * us * nsTs[0];
        const float f = squash_scale(n2) * us;
        const float4 sv = ((const float4*)S)[oq];
        float4 ov;
        ov.x = f * sv.x; ov.y = f * sv.y; ov.z = f * sv.z; ov.w = f * sv.w;
        ((float4*)(out + (((b * 64 + t) * 16 + c) << 4)))[oq] = ov;
    }
}

extern "C" void kernel_launch(void* const* d_in, const int* in_sizes, int n_in,
                              void* d_out, int out_size, void* d_ws, size_t ws_size,
                              hipStream_t stream) {
    const float* ui = (const float*)d_in[0];   // [16,64,16]
    const float* W  = (const float*)d_in[1];   // [1,256,16,16,16]
    float* out = (float*)d_out;                // [16,64,16,16]
    float* ws  = (float*)d_ws;

    k1_prep<<<260, 256, 0, stream>>>(ui, W, ws);
    k2_round0<<<256, 256, 0, stream>>>(ws);
    k3_iter<false><<<256, 256, 0, stream>>>(ws, out, OFF_BIJ, OFF_BIJ2);
    k3_iter<true><<<256, 256, 0, stream>>>(ws, out, OFF_BIJ2, OFF_BIJ2);
}

// Round 4
// 42.606 us; speedup vs baseline: 1.7190x; 1.7190x over previous
//
#include <hip/hip_runtime.h>
#include <math.h>

// B=16, T=64, R=256, C=16, D=16, O(=in_dim)=16, NUM_ITERATIONS=3
//
// Factorization: u_hat[b,t,r,c,o] = Wsum[r,c,o]*usum[b,t]
//   Wsum[r,c,o] = sum_d W[r,c,d,o], usum[b,t] = sum_i ui[b,t,i]
// Per routing iter:
//   c_ij = softmax_c(b_ij); S[b,c,o] = sum_r c_ij*Wsum; NS[b,c]=sum_o S^2
//   b_ij += (sum_o Wsum[r,c,o]*S[b,c,o]) * Tsum[b,c],
//   Tsum = sum_t usum^2*squash_scale(usum^2*NS)
// Output: v[b,t,c,o] = squash_scale(usum^2*NS)*usum*S[b,c,o]
// bij starts at 0 -> iter0 softmax is exactly uniform (generic loop handles it).
//
// Design (R3 lesson): launch count + per-kernel latency dominate, not BW.
// => 2 launches: K1 (Wsum layouts), K2 (entire routing, one block per b,
//    bij in LDS, Wsum/WsumT re-read from L2 each phase).

#define OFF_WSUM   0        // [256][16][16] (r,c,o)
#define OFF_WSUMT  65536    // [16][16][256] (c,o,r)

__device__ __forceinline__ float squash_scale(float n2) {
    return n2 / (1.0f + n2) * rsqrtf(n2 + 1e-9f);
}

// K1: Wsum in (r,c,o) and (c,o,r) layouts. grid 256x256.
__global__ void k1_prep(const float* __restrict__ W, float* __restrict__ ws) {
    const int r = blockIdx.x;
    const int tid = threadIdx.x;            // (c,o)
    const int c = tid >> 4, o = tid & 15;
    const float* base = W + r * 4096 + c * 256 + o;
    float s = 0.f;
#pragma unroll
    for (int d = 0; d < 16; ++d) s += base[d * 16];
    ws[OFF_WSUM + r * 256 + tid] = s;
    ws[OFF_WSUMT + tid * 256 + r] = s;
}

// K2: full routing for one b per block. grid 16 x 1024.
__global__ void __launch_bounds__(1024) k2_route(const float* __restrict__ ui,
                                                 const float* __restrict__ ws,
                                                 float* __restrict__ out) {
    __shared__ float usum_sh[64];
    __shared__ float bij[256][17];     // padded: stride 17 -> conflict-free rows
    __shared__ float cijT[16][256];    // [c][r]
    __shared__ float S_sh[256];        // [c*16+o]
    __shared__ float NS_sh[16];
    __shared__ float Ts_sh[16];
    const int b = blockIdx.x;
    const int tid = threadIdx.x;

    // usum[b,t]: threads 0..63, vectorized
    if (tid < 64) {
        const float4* u4 = (const float4*)(ui + b * 1024 + tid * 16);
        float4 a = u4[0], e = u4[1], f = u4[2], g = u4[3];
        usum_sh[tid] = ((a.x + a.y) + (a.z + a.w)) + ((e.x + e.y) + (e.z + e.w))
                     + ((f.x + f.y) + (f.z + f.w)) + ((g.x + g.y) + (g.z + g.w));
    }
    for (int idx = tid; idx < 256 * 17; idx += 1024) ((float*)bij)[idx] = 0.f;
    __syncthreads();

    for (int it = 0; it < 3; ++it) {
        // A: softmax over c of bij[r,:] (threads 0..255; iter0: zeros -> 1/16)
        if (tid < 256) {
            float v[16];
#pragma unroll
            for (int c = 0; c < 16; ++c) v[c] = bij[tid][c];
            float m = v[0];
#pragma unroll
            for (int c = 1; c < 16; ++c) m = fmaxf(m, v[c]);
            float sum = 0.f;
#pragma unroll
            for (int c = 0; c < 16; ++c) { v[c] = __expf(v[c] - m); sum += v[c]; }
            const float inv = 1.0f / sum;
#pragma unroll
            for (int c = 0; c < 16; ++c) cijT[c][tid] = v[c] * inv;
        }
        __syncthreads();

        // B: S[c,o] = sum_r cij[r]*WsumT[c,o,r]; tid=(c,o,rs), rs splits r 4-way
        {
            const int c = tid >> 6, o = (tid >> 2) & 15, rs = tid & 3;
            const float4* wt = (const float4*)(ws + OFF_WSUMT + (c * 16 + o) * 256 + rs * 64);
            const float4* cr = (const float4*)(&cijT[c][rs * 64]);
            float acc = 0.f;
#pragma unroll
            for (int q = 0; q < 16; ++q) {
                float4 w = wt[q]; float4 cv = cr[q];
                acc += cv.x * w.x + cv.y * w.y + cv.z * w.z + cv.w * w.w;
            }
            acc += __shfl_down(acc, 1, 4);
            acc += __shfl_down(acc, 2, 4);
            if (rs == 0) S_sh[c * 16 + o] = acc;
        }
        __syncthreads();

        // C: NS[c] (threads 0..15)
        if (tid < 16) {
            float ns = 0.f;
#pragma unroll
            for (int o = 0; o < 16; ++o) { float s = S_sh[tid * 16 + o]; ns += s * s; }
            NS_sh[tid] = ns;
        }
        __syncthreads();

        if (it < 2) {
            // D: Tsum[c] = sum_t us^2*squash_scale(us^2*NS[c]); one wave per c
            {
                const int c = tid >> 6, t = tid & 63;
                const float us = usum_sh[t];
                const float us2 = us * us;
                float v = us2 * squash_scale(us2 * NS_sh[c]);
#pragma unroll
                for (int off = 32; off > 0; off >>= 1) v += __shfl_down(v, off, 64);
                if (t == 0) Ts_sh[c] = v;
            }
            __syncthreads();
            // E: bij[r][c] += (sum_o Wsum[r,c,o]*S[c,o]) * Ts[c]; 4 pairs/thread
#pragma unroll
            for (int k = 0; k < 4; ++k) {
                const int p = k * 1024 + tid;
                const int r = p >> 4, c = p & 15;
                const float4* w4 = (const float4*)(ws + OFF_WSUM + r * 256 + c * 16);
                const float4* s4 = (const float4*)(S_sh + c * 16);
                float wsv = 0.f;
#pragma unroll
                for (int q = 0; q < 4; ++q) {
                    float4 w = w4[q]; float4 sv = s4[q];
                    wsv += w.x * sv.x + w.y * sv.y + w.z * sv.z + w.w * sv.w;
                }
                bij[r][c] += wsv * Ts_sh[c];
            }
            __syncthreads();
        }
    }

    // F: v[b,t,c,o] = squash_scale(us^2*NS[c])*us*S[c,o]; tid=(t,c)
    {
        const int t = tid >> 4, c = tid & 15;
        const float us = usum_sh[t];
        const float n2 = us * us * NS_sh[c];
        const float f = squash_scale(n2) * us;
        float4* o4 = (float4*)(out + (((b * 64 + t) * 16 + c) << 4));
        const float4* s4 = (const float4*)(S_sh + c * 16);
#pragma unroll
        for (int q = 0; q < 4; ++q) {
            float4 sv = s4[q];
            float4 ov;
            ov.x = f * sv.x; ov.y = f * sv.y; ov.z = f * sv.z; ov.w = f * sv.w;
            o4[q] = ov;
        }
    }
}

extern "C" void kernel_launch(void* const* d_in, const int* in_sizes, int n_in,
                              void* d_out, int out_size, void* d_ws, size_t ws_size,
                              hipStream_t stream) {
    const float* ui = (const float*)d_in[0];   // [16,64,16]
    const float* W  = (const float*)d_in[1];   // [1,256,16,16,16]
    float* out = (float*)d_out;                // [16,64,16,16]
    float* ws  = (float*)d_ws;

    k1_prep<<<256, 256, 0, stream>>>(W, ws);
    k2_route<<<16, 1024, 0, stream>>>(ui, ws, out);
}